// Round 4
// baseline (516.818 us; speedup 1.0000x reference)
//
#include <hip/hip_runtime.h>

// GCN scatter-aggregate, round 10: round-1 sort pipeline + full-line pairs writes.
//   k_pre   : Wf fragment conversion || zero gcur + dummy h2 row
//   k_part  : coarse radix partition; per-bucket runs PADDED to 64B lines
//             (dummy pairs src=N) -> all global scatter writes are full lines
//   k_scanb : scan of padded bucket totals -> cbase; rowptr[N] = total
//   k_fine  : per-bucket counting sort (dummies filtered); emits rowptr, dis,
//             srcs (bucket gap filled with N)
//   k_gemm  : h = bf16(dis * (x @ W))  (MFMA, fp32 accumulate)
//   k_aggr  : out[n] = dis[n] * sum(h[srcs]) + bias  (dummy rows add 0)
// Inputs: x fp32 [N,256], edge_index int32 [2,E] (row=dst, col=src),
//         W fp32 [256,128], bias fp32 [128]. Output fp32 [N,128].

#define N_FEAT 256
#define N_HID  128
#define D_BITS 8   // coarse bucket = dst >> 8 (256 dsts/bucket)
#define NBMAX 392  // ceil(100000/256) = 391
#define CAP  6144  // per-bucket capacity (padded mean 5460, +9 sigma margin)
#define TILE 4096  // edges per k_part block

typedef float fx4    __attribute__((ext_vector_type(4)));
typedef float f32x16 __attribute__((ext_vector_type(16)));
typedef short bf16x8 __attribute__((ext_vector_type(8)));
typedef unsigned int u32x4 __attribute__((ext_vector_type(4)));

__device__ __forceinline__ float bf2f(unsigned int u) {
    return __uint_as_float(u << 16);
}
__device__ __forceinline__ float bf2f_hi(unsigned int u) {
    return __uint_as_float(u & 0xFFFF0000u);
}
__device__ __forceinline__ unsigned int f2bf(float f) {
    unsigned int u = __float_as_uint(f);
    return (u + 0x7FFFu + ((u >> 16) & 1u)) >> 16;  // round-nearest-even
}

// ---- k_pre: Wf fragment conversion + gcur/dummy-row zero --------------------
// Blocks 0..15: W -> fragment-ready bf16 (B-operand of mfma_f32_32x32x16_bf16).
// Frag f = kstep*4 + ntile; lane supplies B[k=kstep*16+(lane>>5)*8+j][n=ntile*32+(lane&31)].
// Block 16: zero gcur (512 ints) + dummy h2 row (tail/pad target of k_aggr).
__global__ __launch_bounds__(256) void k_pre(const float* __restrict__ W,
                                             uint4* __restrict__ Wf,
                                             int* __restrict__ gcur,
                                             unsigned int* __restrict__ h2d) {
    const int b = blockIdx.x, t = threadIdx.x;
    if (b < 16) {
        int i = b * 256 + t;                  // 0..4095
        int lane = i & 63, f = i >> 6;
        int kstep = f >> 2, nt = f & 3;
        int n  = nt * 32 + (lane & 31);
        int kb = kstep * 16 + (lane >> 5) * 8;
        unsigned s[8];
#pragma unroll
        for (int j = 0; j < 8; ++j) s[j] = f2bf(W[(kb + j) * N_HID + n]);
        uint4 o;
        o.x = s[0] | (s[1] << 16);
        o.y = s[2] | (s[3] << 16);
        o.z = s[4] | (s[5] << 16);
        o.w = s[6] | (s[7] << 16);
        Wf[i] = o;
    } else {
        gcur[t]       = 0;
        gcur[t + 256] = 0;
        if (t < 64) h2d[t] = 0;               // dummy zero row h2[N]
    }
}

// ---- pass 1: partition edges into coarse buckets, 64B-aligned runs ----------
__global__ __launch_bounds__(256) void k_part(const int* __restrict__ ei,
                                              int* __restrict__ gcur,
                                              uint2* __restrict__ pairs,
                                              int E, int nb, int N) {
    __shared__ int hist[NBMAX], lbase[NBMAX], gbase[NBMAX], cur[NBMAX];
    __shared__ int sc[256];
    __shared__ uint2 sorted[TILE];   // 32 KB
    const int t  = threadIdx.x;
    const int e0 = blockIdx.x * TILE;
    const int cnt = min(TILE, E - e0);

    for (int b = t; b < nb; b += 256) hist[b] = 0;
    __syncthreads();
    for (int i = t; i < cnt; i += 256)
        atomicAdd(&hist[ei[e0 + i] >> D_BITS], 1);
    __syncthreads();

    int v0 = (2 * t     < nb) ? hist[2 * t]     : 0;
    int v1 = (2 * t + 1 < nb) ? hist[2 * t + 1] : 0;
    sc[t] = v0 + v1;
    __syncthreads();
    for (int off = 1; off < 256; off <<= 1) {
        int a = sc[t];
        int b2 = (t >= off) ? sc[t - off] : 0;
        __syncthreads();
        sc[t] = a + b2;
        __syncthreads();
    }
    int ex = sc[t] - (v0 + v1);
    if (2 * t     < nb) lbase[2 * t]     = ex;
    if (2 * t + 1 < nb) lbase[2 * t + 1] = ex + v0;
    __syncthreads();

    // reserve PADDED run (multiple of 8 pairs = 64B) per bucket
    for (int b = t; b < nb; b += 256) {
        int h  = hist[b];
        int hp = (h + 7) & ~7;
        gbase[b] = (hp > 0) ? atomicAdd(&gcur[b], hp) : 0;
        cur[b] = lbase[b];
    }
    __syncthreads();

    for (int i = t; i < cnt; i += 256) {
        int d = ei[e0 + i];
        int s = ei[E + e0 + i];
        int b = d >> D_BITS;
        int p = atomicAdd(&cur[b], 1);
        sorted[p] = make_uint2((unsigned)s, (unsigned)d);
    }
    __syncthreads();

    // emit real pairs (coalesced, line-aligned runs)
    for (int i = t; i < cnt; i += 256) {
        uint2 pr = sorted[i];
        int b = ((int)pr.y) >> D_BITS;
        pairs[(size_t)b * CAP + gbase[b] + (i - lbase[b])] = pr;
    }
    // complete each run's last line with dummies (src=N => filtered/zero)
    for (int b = t; b < nb; b += 256) {
        int h  = hist[b];
        int hp = (h + 7) & ~7;
        size_t base = (size_t)b * CAP + gbase[b];
        uint2 dmy = make_uint2((unsigned)N, (unsigned)(b << D_BITS));
        for (int k = h; k < hp; ++k) pairs[base + k] = dmy;
    }
}

// ---- scan of padded bucket totals -> bucket bases; rowptr[N] = total --------
__global__ __launch_bounds__(256) void k_scanb(const int* __restrict__ gcur,
                                               int* __restrict__ cbase,
                                               int* __restrict__ rowptr,
                                               int nb, int N) {
    __shared__ int sc[256];
    int t = threadIdx.x;
    int v0 = (2 * t     < nb) ? gcur[2 * t]     : 0;
    int v1 = (2 * t + 1 < nb) ? gcur[2 * t + 1] : 0;
    sc[t] = v0 + v1;
    __syncthreads();
    for (int off = 1; off < 256; off <<= 1) {
        int a = sc[t];
        int b = (t >= off) ? sc[t - off] : 0;
        __syncthreads();
        sc[t] = a + b;
        __syncthreads();
    }
    int ex = sc[t] - (v0 + v1);
    if (2 * t     < nb) cbase[2 * t]     = ex;
    if (2 * t + 1 < nb) cbase[2 * t + 1] = ex + v0;
    if (t == 255) rowptr[N] = sc[255];    // total incl. dummies
}

// ---- pass 2: per-bucket counting sort (dummies filtered) --------------------
__global__ __launch_bounds__(256) void k_fine(const uint2* __restrict__ pairs,
                                              const int* __restrict__ gcur,
                                              const int* __restrict__ cbase,
                                              int* __restrict__ rowptr,
                                              float* __restrict__ dis,
                                              int* __restrict__ srcs,
                                              int N) {
    __shared__ int hist[256], cur[256], sc[256];
    const int t = threadIdx.x;
    const int b = blockIdx.x;
    const int nbk  = gcur[b];          // padded count (incl. dummies)
    const int base = cbase[b];
    const uint2* pp = pairs + (size_t)b * CAP;

    hist[t] = 0;
    __syncthreads();
    for (int i = t; i < nbk; i += 256) {
        uint2 pr = pp[i];
        if (pr.x != (unsigned)N) atomicAdd(&hist[pr.y & 255], 1);
    }
    __syncthreads();

    int h = hist[t];
    sc[t] = h;
    __syncthreads();
    for (int off = 1; off < 256; off <<= 1) {
        int a = sc[t];
        int b2 = (t >= off) ? sc[t - off] : 0;
        __syncthreads();
        sc[t] = a + b2;
        __syncthreads();
    }
    int ex = sc[t] - h;
    cur[t] = ex;
    int d = (b << D_BITS) + t;
    if (d < N) {
        rowptr[d] = base + ex;
        dis[d] = (h > 0) ? rsqrtf((float)h) : 0.0f;
    }
    __syncthreads();

    for (int i = t; i < nbk; i += 256) {
        uint2 pr = pp[i];
        if (pr.x != (unsigned)N) {
            int p = atomicAdd(&cur[pr.y & 255], 1);
            srcs[base + p] = (int)pr.x;
        }
    }
    // fill bucket's trailing gap (dummy slots) so segments read h2[N]=0
    int R = sc[255];                   // real total in bucket
    for (int i = R + t; i < nbk; i += 256) srcs[base + i] = N;
}

// ---- h = bf16(dis * (x @ W)) via MFMA, no LDS -------------------------------
// Block = 4 waves; wave w covers rows mbase+w*32 .. +31, all 128 cols.
__global__ __launch_bounds__(256) void k_gemm(const float* __restrict__ x,
                                              const uint4* __restrict__ Wf,
                                              const float* __restrict__ dis,
                                              unsigned short* __restrict__ h2s,
                                              int N) {
    const int wave = threadIdx.x >> 6;
    const int lane = threadIdx.x & 63;
    const int half = lane >> 5;          // k sub-block 0/1 (8 elems each)
    const int lm   = lane & 31;
    const int mbase = blockIdx.x * 128 + wave * 32;
    const int arow  = min(mbase + lm, N - 1);   // clamp; garbage rows discarded

    const fx4* xr = (const fx4*)(x + (size_t)arow * N_FEAT) + half * 2;

    f32x16 acc0 = {0}, acc1 = {0}, acc2 = {0}, acc3 = {0};

#pragma unroll
    for (int ks = 0; ks < 16; ++ks) {
        fx4 a0 = xr[ks * 4];          // k = ks*16 + half*8 + (0..3)
        fx4 a1 = xr[ks * 4 + 1];      //                  + (4..7)
        union { bf16x8 v; unsigned u[4]; } A;
        A.u[0] = f2bf(a0.x) | (f2bf(a0.y) << 16);
        A.u[1] = f2bf(a0.z) | (f2bf(a0.w) << 16);
        A.u[2] = f2bf(a1.x) | (f2bf(a1.y) << 16);
        A.u[3] = f2bf(a1.z) | (f2bf(a1.w) << 16);
        union { bf16x8 v; uint4 q; } B0, B1, B2, B3;
        B0.q = Wf[(ks * 4 + 0) * 64 + lane];
        B1.q = Wf[(ks * 4 + 1) * 64 + lane];
        B2.q = Wf[(ks * 4 + 2) * 64 + lane];
        B3.q = Wf[(ks * 4 + 3) * 64 + lane];
        acc0 = __builtin_amdgcn_mfma_f32_32x32x16_bf16(A.v, B0.v, acc0, 0, 0, 0);
        acc1 = __builtin_amdgcn_mfma_f32_32x32x16_bf16(A.v, B1.v, acc1, 0, 0, 0);
        acc2 = __builtin_amdgcn_mfma_f32_32x32x16_bf16(A.v, B2.v, acc2, 0, 0, 0);
        acc3 = __builtin_amdgcn_mfma_f32_32x32x16_bf16(A.v, B3.v, acc3, 0, 0, 0);
    }

    // C/D: col = lane&31, row = (r&3) + 8*(r>>2) + 4*(lane>>5)   [m74/m101]
#pragma unroll
    for (int r = 0; r < 16; ++r) {
        int row  = (r & 3) + 8 * (r >> 2) + 4 * half;
        int node = mbase + row;
        if (node < N) {
            float dn = dis[node];
            size_t o = (size_t)node * N_HID + lm;
            h2s[o +  0] = (unsigned short)f2bf(dn * acc0[r]);
            h2s[o + 32] = (unsigned short)f2bf(dn * acc1[r]);
            h2s[o + 64] = (unsigned short)f2bf(dn * acc2[r]);
            h2s[o + 96] = (unsigned short)f2bf(dn * acc3[r]);
        }
    }
}

// ---- aggregation: out[n] = dis[n] * sum(h[srcs]) + bias ---------------------
// One wave per node. 16-edge chunks: one coalesced srcs read, ds_bpermute
// distribution, 4x dwordx4 gathers (each covers 4 edge rows = 1 KB).
// Lane-group j = lane>>4 handles edge 4g+j of the chunk; lane q = lane&15
// holds hidden dims 8q..8q+7. Tail edges clamp to zeroed dummy row h2[N];
// in-segment dummy entries (src=N) gather the same zero row.
__global__ __launch_bounds__(256) void k_aggr(const int* __restrict__ rowptr,
                                              const int* __restrict__ srcs,
                                              const u32x4* __restrict__ h2q,
                                              const float* __restrict__ dis,
                                              const float* __restrict__ bias,
                                              float4* __restrict__ out4, int N) {
    const int n    = blockIdx.x * 4 + (threadIdx.x >> 6);
    const int lane = threadIdx.x & 63;
    if (n >= N) return;
    const int j = lane >> 4;      // edge sub-slot within each gather
    const int q = lane & 15;      // 16B chunk (dims 8q..8q+7) within a row

    int i   = rowptr[n];
    int end = rowptr[n + 1];
    float dn = dis[n];            // hoisted: overlaps with srcs/gather latency

    float a[8];
#pragma unroll
    for (int k = 0; k < 8; ++k) a[k] = 0.0f;

    for (; i < end; i += 16) {
        // one coalesced 64B read covers 16 src ids (srcs padded by 16 ints)
        int cl = srcs[i + q];
#pragma unroll
        for (int g = 0; g < 4; ++g) {
            int cg  = __shfl(cl, 4 * g + j, 64);   // ds_bpermute
            int idx = i + 4 * g + j;
            cg = (idx < end) ? cg : N;             // dummy zero row for tail
            u32x4 v = h2q[(size_t)cg * 16 + q];    // dwordx4: 4 rows / instr
            a[0] += bf2f(v[0]);  a[1] += bf2f_hi(v[0]);
            a[2] += bf2f(v[1]);  a[3] += bf2f_hi(v[1]);
            a[4] += bf2f(v[2]);  a[5] += bf2f_hi(v[2]);
            a[6] += bf2f(v[3]);  a[7] += bf2f_hi(v[3]);
        }
    }

    // sum the 4 lane-groups (once per node)
#pragma unroll
    for (int k = 0; k < 8; ++k) {
        a[k] += __shfl_xor(a[k], 16, 64);
        a[k] += __shfl_xor(a[k], 32, 64);
    }

    if (lane < 16) {
        const float4* b4 = (const float4*)bias;
        float4 b0 = b4[q * 2], b1 = b4[q * 2 + 1];
        float4 o0, o1;
        o0.x = dn * a[0] + b0.x;  o0.y = dn * a[1] + b0.y;
        o0.z = dn * a[2] + b0.z;  o0.w = dn * a[3] + b0.w;
        o1.x = dn * a[4] + b1.x;  o1.y = dn * a[5] + b1.y;
        o1.z = dn * a[6] + b1.z;  o1.w = dn * a[7] + b1.w;
        out4[(size_t)n * 32 + q * 2]     = o0;
        out4[(size_t)n * 32 + q * 2 + 1] = o1;
    }
}

extern "C" void kernel_launch(void* const* d_in, const int* in_sizes, int n_in,
                              void* d_out, int out_size, void* d_ws, size_t ws_size,
                              hipStream_t stream) {
    const float* x    = (const float*)d_in[0];   // fp32 [N,256]
    const int*   ei   = (const int*)d_in[1];     // int32 [2,E]
    const float* W    = (const float*)d_in[2];   // fp32 [256,128]
    const float* bias = (const float*)d_in[3];   // fp32 [128]

    const int N = in_sizes[0] / N_FEAT;   // 100000
    const int E = in_sizes[1] / 2;        // 1600000
    const int nb = (N + 255) >> D_BITS;   // 391 coarse buckets

    // workspace layout (~56 MB)
    char* ws = (char*)d_ws;
    size_t off = 0;
    int*          gcur   = (int*)(ws + off);   off += 512 * 4;
    int*          cbase  = (int*)(ws + off);   off += 512 * 4;
    int*          rowptr = (int*)(ws + off);   off += (size_t)(N + 1) * 4 + 12;
    float*        dis    = (float*)(ws + off); off += (size_t)N * 4;
    int*          srcs   = (int*)(ws + off);   off += (size_t)nb * CAP * 4 + 64;
    uint4*        Wf     = (uint4*)(ws + off); off += 4096 * 16;   // 64 KB
    uint2*        pairs  = (uint2*)(ws + off); off += (size_t)nb * CAP * 8;
    unsigned int* h2     = (unsigned int*)(ws + off);  // (N+1)*64 dwords

    k_pre<<<17, 256, 0, stream>>>(W, (uint4*)Wf, gcur, h2 + (size_t)N * 64);
    k_part<<<(E + TILE - 1) / TILE, 256, 0, stream>>>(ei, gcur, pairs, E, nb, N);
    k_scanb<<<1, 256, 0, stream>>>(gcur, cbase, rowptr, nb, N);
    k_fine<<<nb, 256, 0, stream>>>(pairs, gcur, cbase, rowptr, dis, srcs, N);
    k_gemm<<<(N + 127) / 128, 256, 0, stream>>>(x, Wf, dis,
                                                (unsigned short*)h2, N);
    k_aggr<<<(N + 3) / 4, 256, 0, stream>>>(rowptr, srcs, (const u32x4*)h2,
                                            dis, bias, (float4*)d_out, N);
}

// Round 5
// 325.237 us; speedup vs baseline: 1.5891x; 1.5891x over previous
//
#include <hip/hip_runtime.h>

// GCN scatter-aggregate, round 11: in-LDS line padding + explicit segment ends.
//   k_pre   : Wf fragment conversion || zero gcur + dummy h2 row
//   k_part  : coarse radix partition; per-bucket runs padded to 8 pairs (64B)
//             IN LDS (dummy pairs src=N) -> every global pairs line is written
//             exactly once, fully, coalesced
//   k_scanb : scan of padded bucket totals -> cbase
//   k_fine  : per-bucket counting sort (dummies filtered); emits rowptr, rend,
//             dis, srcs
//   k_gemm  : h = bf16(dis * (x @ W))  (MFMA, fp32 accumulate)
//   k_aggr  : out[n] = dis[n] * sum(h[srcs[rowptr[n]..rend[n]]]) + bias
// Inputs: x fp32 [N,256], edge_index int32 [2,E] (row=dst, col=src),
//         W fp32 [256,128], bias fp32 [128]. Output fp32 [N,128].

#define N_FEAT 256
#define N_HID  128
#define D_BITS 8    // coarse bucket = dst >> 8 (256 dsts/bucket)
#define NBMAX 392   // ceil(100000/256) = 391
#define CAP  6144   // per-bucket capacity (padded mean ~5503, +8 sigma margin)
#define TILE 4096   // edges per k_part block
#define PADTILE 6848  // TILE + NBMAX*7 rounded up (max padded block total 6833)

typedef float fx4    __attribute__((ext_vector_type(4)));
typedef float f32x16 __attribute__((ext_vector_type(16)));
typedef short bf16x8 __attribute__((ext_vector_type(8)));
typedef unsigned int u32x4 __attribute__((ext_vector_type(4)));

__device__ __forceinline__ float bf2f(unsigned int u) {
    return __uint_as_float(u << 16);
}
__device__ __forceinline__ float bf2f_hi(unsigned int u) {
    return __uint_as_float(u & 0xFFFF0000u);
}
__device__ __forceinline__ unsigned int f2bf(float f) {
    unsigned int u = __float_as_uint(f);
    return (u + 0x7FFFu + ((u >> 16) & 1u)) >> 16;  // round-nearest-even
}

// ---- k_pre: Wf fragment conversion + gcur/dummy-row zero --------------------
// Blocks 0..15: W -> fragment-ready bf16 (B-operand of mfma_f32_32x32x16_bf16).
// Frag f = kstep*4 + ntile; lane supplies B[k=kstep*16+(lane>>5)*8+j][n=ntile*32+(lane&31)].
// Block 16: zero gcur (512 ints) + dummy h2 row (clamp target of k_aggr).
__global__ __launch_bounds__(256) void k_pre(const float* __restrict__ W,
                                             uint4* __restrict__ Wf,
                                             int* __restrict__ gcur,
                                             unsigned int* __restrict__ h2d) {
    const int b = blockIdx.x, t = threadIdx.x;
    if (b < 16) {
        int i = b * 256 + t;                  // 0..4095
        int lane = i & 63, f = i >> 6;
        int kstep = f >> 2, nt = f & 3;
        int n  = nt * 32 + (lane & 31);
        int kb = kstep * 16 + (lane >> 5) * 8;
        unsigned s[8];
#pragma unroll
        for (int j = 0; j < 8; ++j) s[j] = f2bf(W[(kb + j) * N_HID + n]);
        uint4 o;
        o.x = s[0] | (s[1] << 16);
        o.y = s[2] | (s[3] << 16);
        o.z = s[4] | (s[5] << 16);
        o.w = s[6] | (s[7] << 16);
        Wf[i] = o;
    } else {
        gcur[t]       = 0;
        gcur[t + 256] = 0;
        if (t < 64) h2d[t] = 0;               // dummy zero row h2[N]
    }
}

// ---- pass 1: partition edges into coarse buckets, full-line runs ------------
// Per-bucket runs padded to multiples of 8 pairs (64B) inside LDS; dummies
// (src=N, dst=b<<8) occupy pad slots so the emit loop writes whole lines.
__global__ __launch_bounds__(256) void k_part(const int* __restrict__ ei,
                                              int* __restrict__ gcur,
                                              uint2* __restrict__ pairs,
                                              int E, int nb, int N) {
    __shared__ int hist[NBMAX], lbase[NBMAX], gbase[NBMAX], cur[NBMAX];
    __shared__ int sc[256];
    __shared__ uint2 sorted[PADTILE];   // 54.8 KB
    const int t  = threadIdx.x;
    const int e0 = blockIdx.x * TILE;
    const int cnt = min(TILE, E - e0);

    for (int b = t; b < nb; b += 256) hist[b] = 0;
    __syncthreads();
    for (int i = t; i < cnt; i += 256)
        atomicAdd(&hist[ei[e0 + i] >> D_BITS], 1);
    __syncthreads();

    // scan over PADDED counts -> padded local bases
    int h0 = (2 * t     < nb) ? hist[2 * t]     : 0;
    int h1 = (2 * t + 1 < nb) ? hist[2 * t + 1] : 0;
    int v0 = (h0 + 7) & ~7;
    int v1 = (h1 + 7) & ~7;
    sc[t] = v0 + v1;
    __syncthreads();
    for (int off = 1; off < 256; off <<= 1) {
        int a = sc[t];
        int b2 = (t >= off) ? sc[t - off] : 0;
        __syncthreads();
        sc[t] = a + b2;
        __syncthreads();
    }
    int ex = sc[t] - (v0 + v1);
    if (2 * t     < nb) lbase[2 * t]     = ex;
    if (2 * t + 1 < nb) lbase[2 * t + 1] = ex + v0;
    __syncthreads();
    const int P = sc[255];              // padded block total (<= PADTILE)

    // reserve padded run per bucket; pre-fill pad slots with dummies (LDS)
    for (int b = t; b < nb; b += 256) {
        int h  = hist[b];
        int hp = (h + 7) & ~7;
        gbase[b] = (hp > 0) ? atomicAdd(&gcur[b], hp) : 0;
        cur[b] = lbase[b];
        uint2 dmy = make_uint2((unsigned)N, (unsigned)(b << D_BITS));
        for (int k = h; k < hp; ++k) sorted[lbase[b] + k] = dmy;
    }
    __syncthreads();

    for (int i = t; i < cnt; i += 256) {
        int d = ei[e0 + i];
        int s = ei[E + e0 + i];
        int b = d >> D_BITS;
        int p = atomicAdd(&cur[b], 1);
        sorted[p] = make_uint2((unsigned)s, (unsigned)d);
    }
    __syncthreads();

    // emit padded runs: coalesced, every 64B line written exactly once
    for (int i = t; i < P; i += 256) {
        uint2 pr = sorted[i];
        int b = ((int)pr.y) >> D_BITS;
        pairs[(size_t)b * CAP + gbase[b] + (i - lbase[b])] = pr;
    }
}

// ---- scan of padded bucket totals -> bucket bases ---------------------------
__global__ __launch_bounds__(256) void k_scanb(const int* __restrict__ gcur,
                                               int* __restrict__ cbase,
                                               int nb) {
    __shared__ int sc[256];
    int t = threadIdx.x;
    int v0 = (2 * t     < nb) ? gcur[2 * t]     : 0;
    int v1 = (2 * t + 1 < nb) ? gcur[2 * t + 1] : 0;
    sc[t] = v0 + v1;
    __syncthreads();
    for (int off = 1; off < 256; off <<= 1) {
        int a = sc[t];
        int b = (t >= off) ? sc[t - off] : 0;
        __syncthreads();
        sc[t] = a + b;
        __syncthreads();
    }
    int ex = sc[t] - (v0 + v1);
    if (2 * t     < nb) cbase[2 * t]     = ex;
    if (2 * t + 1 < nb) cbase[2 * t + 1] = ex + v0;
}

// ---- pass 2: per-bucket counting sort (dummies filtered) --------------------
// Emits rowptr (segment start), rend (segment end), dis, srcs. Segments are
// tight: dummy pad slots live only in inter-segment gaps nothing reads.
__global__ __launch_bounds__(256) void k_fine(const uint2* __restrict__ pairs,
                                              const int* __restrict__ gcur,
                                              const int* __restrict__ cbase,
                                              int* __restrict__ rowptr,
                                              int* __restrict__ rend,
                                              float* __restrict__ dis,
                                              int* __restrict__ srcs,
                                              int N) {
    __shared__ int hist[256], cur[256], sc[256];
    const int t = threadIdx.x;
    const int b = blockIdx.x;
    const int nbk  = gcur[b];          // padded count (incl. dummies)
    const int base = cbase[b];
    const uint2* pp = pairs + (size_t)b * CAP;

    hist[t] = 0;
    __syncthreads();
    for (int i = t; i < nbk; i += 256) {
        uint2 pr = pp[i];
        if (pr.x != (unsigned)N) atomicAdd(&hist[pr.y & 255], 1);
    }
    __syncthreads();

    int h = hist[t];
    sc[t] = h;
    __syncthreads();
    for (int off = 1; off < 256; off <<= 1) {
        int a = sc[t];
        int b2 = (t >= off) ? sc[t - off] : 0;
        __syncthreads();
        sc[t] = a + b2;
        __syncthreads();
    }
    int ex = sc[t] - h;
    cur[t] = ex;
    int d = (b << D_BITS) + t;
    if (d < N) {
        rowptr[d] = base + ex;
        rend[d]   = base + ex + h;
        dis[d] = (h > 0) ? rsqrtf((float)h) : 0.0f;
    }
    __syncthreads();

    for (int i = t; i < nbk; i += 256) {
        uint2 pr = pp[i];
        if (pr.x != (unsigned)N) {
            int p = atomicAdd(&cur[pr.y & 255], 1);
            srcs[base + p] = (int)pr.x;
        }
    }
}

// ---- h = bf16(dis * (x @ W)) via MFMA, no LDS -------------------------------
// Block = 4 waves; wave w covers rows mbase+w*32 .. +31, all 128 cols.
__global__ __launch_bounds__(256) void k_gemm(const float* __restrict__ x,
                                              const uint4* __restrict__ Wf,
                                              const float* __restrict__ dis,
                                              unsigned short* __restrict__ h2s,
                                              int N) {
    const int wave = threadIdx.x >> 6;
    const int lane = threadIdx.x & 63;
    const int half = lane >> 5;          // k sub-block 0/1 (8 elems each)
    const int lm   = lane & 31;
    const int mbase = blockIdx.x * 128 + wave * 32;
    const int arow  = min(mbase + lm, N - 1);   // clamp; garbage rows discarded

    const fx4* xr = (const fx4*)(x + (size_t)arow * N_FEAT) + half * 2;

    f32x16 acc0 = {0}, acc1 = {0}, acc2 = {0}, acc3 = {0};

#pragma unroll
    for (int ks = 0; ks < 16; ++ks) {
        fx4 a0 = xr[ks * 4];          // k = ks*16 + half*8 + (0..3)
        fx4 a1 = xr[ks * 4 + 1];      //                  + (4..7)
        union { bf16x8 v; unsigned u[4]; } A;
        A.u[0] = f2bf(a0.x) | (f2bf(a0.y) << 16);
        A.u[1] = f2bf(a0.z) | (f2bf(a0.w) << 16);
        A.u[2] = f2bf(a1.x) | (f2bf(a1.y) << 16);
        A.u[3] = f2bf(a1.z) | (f2bf(a1.w) << 16);
        union { bf16x8 v; uint4 q; } B0, B1, B2, B3;
        B0.q = Wf[(ks * 4 + 0) * 64 + lane];
        B1.q = Wf[(ks * 4 + 1) * 64 + lane];
        B2.q = Wf[(ks * 4 + 2) * 64 + lane];
        B3.q = Wf[(ks * 4 + 3) * 64 + lane];
        acc0 = __builtin_amdgcn_mfma_f32_32x32x16_bf16(A.v, B0.v, acc0, 0, 0, 0);
        acc1 = __builtin_amdgcn_mfma_f32_32x32x16_bf16(A.v, B1.v, acc1, 0, 0, 0);
        acc2 = __builtin_amdgcn_mfma_f32_32x32x16_bf16(A.v, B2.v, acc2, 0, 0, 0);
        acc3 = __builtin_amdgcn_mfma_f32_32x32x16_bf16(A.v, B3.v, acc3, 0, 0, 0);
    }

    // C/D: col = lane&31, row = (r&3) + 8*(r>>2) + 4*(lane>>5)   [m74/m101]
#pragma unroll
    for (int r = 0; r < 16; ++r) {
        int row  = (r & 3) + 8 * (r >> 2) + 4 * half;
        int node = mbase + row;
        if (node < N) {
            float dn = dis[node];
            size_t o = (size_t)node * N_HID + lm;
            h2s[o +  0] = (unsigned short)f2bf(dn * acc0[r]);
            h2s[o + 32] = (unsigned short)f2bf(dn * acc1[r]);
            h2s[o + 64] = (unsigned short)f2bf(dn * acc2[r]);
            h2s[o + 96] = (unsigned short)f2bf(dn * acc3[r]);
        }
    }
}

// ---- aggregation: out[n] = dis[n] * sum(h[srcs]) + bias ---------------------
// One wave per node. 16-edge chunks: one coalesced srcs read, ds_bpermute
// distribution, 4x dwordx4 gathers (each covers 4 edge rows = 1 KB).
// Lane-group j = lane>>4 handles edge 4g+j of the chunk; lane q = lane&15
// holds hidden dims 8q..8q+7. Out-of-segment slots clamp to zero row h2[N].
__global__ __launch_bounds__(256) void k_aggr(const int* __restrict__ rowptr,
                                              const int* __restrict__ rend,
                                              const int* __restrict__ srcs,
                                              const u32x4* __restrict__ h2q,
                                              const float* __restrict__ dis,
                                              const float* __restrict__ bias,
                                              float4* __restrict__ out4, int N) {
    const int n    = blockIdx.x * 4 + (threadIdx.x >> 6);
    const int lane = threadIdx.x & 63;
    if (n >= N) return;
    const int j = lane >> 4;      // edge sub-slot within each gather
    const int q = lane & 15;      // 16B chunk (dims 8q..8q+7) within a row

    int i   = rowptr[n];
    int end = rend[n];
    float dn = dis[n];            // hoisted: overlaps with srcs/gather latency

    float a[8];
#pragma unroll
    for (int k = 0; k < 8; ++k) a[k] = 0.0f;

    for (; i < end; i += 16) {
        // one coalesced 64B read covers 16 src ids (srcs padded allocation)
        int cl = srcs[i + q];
#pragma unroll
        for (int g = 0; g < 4; ++g) {
            int cg  = __shfl(cl, 4 * g + j, 64);   // ds_bpermute
            int idx = i + 4 * g + j;
            cg = (idx < end) ? cg : N;             // dummy zero row for tail
            u32x4 v = h2q[(size_t)cg * 16 + q];    // dwordx4: 4 rows / instr
            a[0] += bf2f(v[0]);  a[1] += bf2f_hi(v[0]);
            a[2] += bf2f(v[1]);  a[3] += bf2f_hi(v[1]);
            a[4] += bf2f(v[2]);  a[5] += bf2f_hi(v[2]);
            a[6] += bf2f(v[3]);  a[7] += bf2f_hi(v[3]);
        }
    }

    // sum the 4 lane-groups (once per node)
#pragma unroll
    for (int k = 0; k < 8; ++k) {
        a[k] += __shfl_xor(a[k], 16, 64);
        a[k] += __shfl_xor(a[k], 32, 64);
    }

    if (lane < 16) {
        const float4* b4 = (const float4*)bias;
        float4 b0 = b4[q * 2], b1 = b4[q * 2 + 1];
        float4 o0, o1;
        o0.x = dn * a[0] + b0.x;  o0.y = dn * a[1] + b0.y;
        o0.z = dn * a[2] + b0.z;  o0.w = dn * a[3] + b0.w;
        o1.x = dn * a[4] + b1.x;  o1.y = dn * a[5] + b1.y;
        o1.z = dn * a[6] + b1.z;  o1.w = dn * a[7] + b1.w;
        out4[(size_t)n * 32 + q * 2]     = o0;
        out4[(size_t)n * 32 + q * 2 + 1] = o1;
    }
}

extern "C" void kernel_launch(void* const* d_in, const int* in_sizes, int n_in,
                              void* d_out, int out_size, void* d_ws, size_t ws_size,
                              hipStream_t stream) {
    const float* x    = (const float*)d_in[0];   // fp32 [N,256]
    const int*   ei   = (const int*)d_in[1];     // int32 [2,E]
    const float* W    = (const float*)d_in[2];   // fp32 [256,128]
    const float* bias = (const float*)d_in[3];   // fp32 [128]

    const int N = in_sizes[0] / N_FEAT;   // 100000
    const int E = in_sizes[1] / 2;        // 1600000
    const int nb = (N + 255) >> D_BITS;   // 391 coarse buckets

    // workspace layout (~57 MB)
    char* ws = (char*)d_ws;
    size_t off = 0;
    int*          gcur   = (int*)(ws + off);   off += 512 * 4;
    int*          cbase  = (int*)(ws + off);   off += 512 * 4;
    int*          rowptr = (int*)(ws + off);   off += (size_t)(N + 4) * 4;
    int*          rend   = (int*)(ws + off);   off += (size_t)(N + 4) * 4;
    float*        dis    = (float*)(ws + off); off += (size_t)N * 4;
    int*          srcs   = (int*)(ws + off);   off += (size_t)nb * CAP * 4 + 64;
    uint4*        Wf     = (uint4*)(ws + off); off += 4096 * 16;   // 64 KB
    uint2*        pairs  = (uint2*)(ws + off); off += (size_t)nb * CAP * 8;
    unsigned int* h2     = (unsigned int*)(ws + off);  // (N+1)*64 dwords

    k_pre<<<17, 256, 0, stream>>>(W, (uint4*)Wf, gcur, h2 + (size_t)N * 64);
    k_part<<<(E + TILE - 1) / TILE, 256, 0, stream>>>(ei, gcur, pairs, E, nb, N);
    k_scanb<<<1, 256, 0, stream>>>(gcur, cbase, nb);
    k_fine<<<nb, 256, 0, stream>>>(pairs, gcur, cbase, rowptr, rend, dis,
                                   srcs, N);
    k_gemm<<<(N + 127) / 128, 256, 0, stream>>>(x, Wf, dis,
                                                (unsigned short*)h2, N);
    k_aggr<<<(N + 3) / 4, 256, 0, stream>>>(rowptr, rend, srcs, (const u32x4*)h2,
                                            dis, bias, (float4*)d_out, N);
}

// Round 7
// 308.549 us; speedup vs baseline: 1.6750x; 1.0541x over previous
//
#include <hip/hip_runtime.h>

// GCN scatter-aggregate, round 13 (= round 12 re-run; container infra failure).
//   k_pre   : Wf fragment conversion || zero gcur + dummy h2 row
//   k_part  : coarse radix partition (1024 thr); per-bucket runs padded to
//             8 pairs (64B) in LDS -> full-line coalesced pairs writes
//   k_scanb : scan of padded bucket totals -> cbase
//   k_fine  : per-bucket counting sort (1024 thr, dummies filtered);
//             emits rowptr, rend, dis, srcs
//   k_gemm  : h = bf16(dis * (x @ W))  (MFMA, fp32 accumulate)
//   k_aggr  : out[n] = dis[n] * sum(h[srcs[rowptr[n]..rend[n]]]) + bias
// Theory: k_part/k_fine were latency-bound at 19% max occupancy
// (391 blocks x 4 waves); 1024-thread blocks quadruple resident waves.
// Inputs: x fp32 [N,256], edge_index int32 [2,E] (row=dst, col=src),
//         W fp32 [256,128], bias fp32 [128]. Output fp32 [N,128].

#define N_FEAT 256
#define N_HID  128
#define D_BITS 8    // coarse bucket = dst >> 8 (256 dsts/bucket)
#define NBMAX 392   // ceil(100000/256) = 391
#define CAP  6144   // per-bucket capacity (padded mean ~5503, +8 sigma margin)
#define TILE 4096   // edges per k_part block
#define PADTILE 6848  // TILE + NBMAX*7 rounded up (max padded block total 6833)

typedef float fx4    __attribute__((ext_vector_type(4)));
typedef float f32x16 __attribute__((ext_vector_type(16)));
typedef short bf16x8 __attribute__((ext_vector_type(8)));
typedef unsigned int u32x4 __attribute__((ext_vector_type(4)));

__device__ __forceinline__ float bf2f(unsigned int u) {
    return __uint_as_float(u << 16);
}
__device__ __forceinline__ float bf2f_hi(unsigned int u) {
    return __uint_as_float(u & 0xFFFF0000u);
}
__device__ __forceinline__ unsigned int f2bf(float f) {
    unsigned int u = __float_as_uint(f);
    return (u + 0x7FFFu + ((u >> 16) & 1u)) >> 16;  // round-nearest-even
}

// ---- k_pre: Wf fragment conversion + gcur/dummy-row zero --------------------
// Blocks 0..15: W -> fragment-ready bf16 (B-operand of mfma_f32_32x32x16_bf16).
// Frag f = kstep*4 + ntile; lane supplies B[k=kstep*16+(lane>>5)*8+j][n=ntile*32+(lane&31)].
// Block 16: zero gcur (512 ints) + dummy h2 row (clamp target of k_aggr).
__global__ __launch_bounds__(256) void k_pre(const float* __restrict__ W,
                                             uint4* __restrict__ Wf,
                                             int* __restrict__ gcur,
                                             unsigned int* __restrict__ h2d) {
    const int b = blockIdx.x, t = threadIdx.x;
    if (b < 16) {
        int i = b * 256 + t;                  // 0..4095
        int lane = i & 63, f = i >> 6;
        int kstep = f >> 2, nt = f & 3;
        int n  = nt * 32 + (lane & 31);
        int kb = kstep * 16 + (lane >> 5) * 8;
        unsigned s[8];
#pragma unroll
        for (int j = 0; j < 8; ++j) s[j] = f2bf(W[(kb + j) * N_HID + n]);
        uint4 o;
        o.x = s[0] | (s[1] << 16);
        o.y = s[2] | (s[3] << 16);
        o.z = s[4] | (s[5] << 16);
        o.w = s[6] | (s[7] << 16);
        Wf[i] = o;
    } else {
        gcur[t]       = 0;
        gcur[t + 256] = 0;
        if (t < 64) h2d[t] = 0;               // dummy zero row h2[N]
    }
}

// ---- pass 1: partition edges into coarse buckets, full-line runs ------------
// 1024 threads (16 waves). Per-bucket runs padded to multiples of 8 pairs
// (64B) inside LDS; dummies (src=N, dst=b<<8) fill pad slots so the emit
// loop writes whole lines, coalesced, exactly once.
__global__ __launch_bounds__(1024) void k_part(const int* __restrict__ ei,
                                               int* __restrict__ gcur,
                                               uint2* __restrict__ pairs,
                                               int E, int nb, int N) {
    __shared__ int hist[NBMAX], lbase[NBMAX], gbase[NBMAX], cur[NBMAX];
    __shared__ int sc[512];
    __shared__ uint2 sorted[PADTILE];   // 54.8 KB (total LDS ~63.1 KB)
    const int t  = threadIdx.x;
    const int e0 = blockIdx.x * TILE;
    const int cnt = min(TILE, E - e0);

    for (int b = t; b < nb; b += 1024) hist[b] = 0;
    __syncthreads();
    for (int i = t; i < cnt; i += 1024)
        atomicAdd(&hist[ei[e0 + i] >> D_BITS], 1);
    __syncthreads();

    // scan over PADDED counts (512 slots, t<512 active; all-thread barriers)
    int v = 0;
    if (t < 512) {
        int h = (t < nb) ? hist[t] : 0;
        v = (h + 7) & ~7;
        sc[t] = v;
    }
    __syncthreads();
    for (int off = 1; off < 512; off <<= 1) {
        int a = 0;
        if (t < 512) { a = sc[t]; if (t >= off) a += sc[t - off]; }
        __syncthreads();
        if (t < 512) sc[t] = a;
        __syncthreads();
    }
    if (t < nb) lbase[t] = sc[t] - v;
    __syncthreads();
    const int P = sc[511];              // padded block total (<= PADTILE)

    // reserve padded run per bucket; pre-fill pad slots with dummies (LDS)
    for (int b = t; b < nb; b += 1024) {
        int h  = hist[b];
        int hp = (h + 7) & ~7;
        gbase[b] = (hp > 0) ? atomicAdd(&gcur[b], hp) : 0;
        cur[b] = lbase[b];
        uint2 dmy = make_uint2((unsigned)N, (unsigned)(b << D_BITS));
        for (int k = h; k < hp; ++k) sorted[lbase[b] + k] = dmy;
    }
    __syncthreads();

    for (int i = t; i < cnt; i += 1024) {
        int d = ei[e0 + i];
        int s = ei[E + e0 + i];
        int b = d >> D_BITS;
        int p = atomicAdd(&cur[b], 1);
        sorted[p] = make_uint2((unsigned)s, (unsigned)d);
    }
    __syncthreads();

    // emit padded runs: coalesced, every 64B line written exactly once
    for (int i = t; i < P; i += 1024) {
        uint2 pr = sorted[i];
        int b = ((int)pr.y) >> D_BITS;
        pairs[(size_t)b * CAP + gbase[b] + (i - lbase[b])] = pr;
    }
}

// ---- scan of padded bucket totals -> bucket bases ---------------------------
__global__ __launch_bounds__(256) void k_scanb(const int* __restrict__ gcur,
                                               int* __restrict__ cbase,
                                               int nb) {
    __shared__ int sc[256];
    int t = threadIdx.x;
    int v0 = (2 * t     < nb) ? gcur[2 * t]     : 0;
    int v1 = (2 * t + 1 < nb) ? gcur[2 * t + 1] : 0;
    sc[t] = v0 + v1;
    __syncthreads();
    for (int off = 1; off < 256; off <<= 1) {
        int a = sc[t];
        int b = (t >= off) ? sc[t - off] : 0;
        __syncthreads();
        sc[t] = a + b;
        __syncthreads();
    }
    int ex = sc[t] - (v0 + v1);
    if (2 * t     < nb) cbase[2 * t]     = ex;
    if (2 * t + 1 < nb) cbase[2 * t + 1] = ex + v0;
}

// ---- pass 2: per-bucket counting sort (1024 thr, dummies filtered) ----------
// Emits rowptr (segment start), rend (segment end), dis, srcs. Segments are
// tight: dummy pad slots live only in inter-segment gaps nothing reads.
__global__ __launch_bounds__(1024) void k_fine(const uint2* __restrict__ pairs,
                                               const int* __restrict__ gcur,
                                               const int* __restrict__ cbase,
                                               int* __restrict__ rowptr,
                                               int* __restrict__ rend,
                                               float* __restrict__ dis,
                                               int* __restrict__ srcs,
                                               int N) {
    __shared__ int hist[256], cur[256], sc[256];
    const int t = threadIdx.x;
    const int b = blockIdx.x;
    const int nbk  = gcur[b];          // padded count (incl. dummies)
    const int base = cbase[b];
    const uint2* pp = pairs + (size_t)b * CAP;

    if (t < 256) hist[t] = 0;
    __syncthreads();
    for (int i = t; i < nbk; i += 1024) {
        uint2 pr = pp[i];
        if (pr.x != (unsigned)N) atomicAdd(&hist[pr.y & 255], 1);
    }
    __syncthreads();

    int h = 0;
    if (t < 256) { h = hist[t]; sc[t] = h; }
    __syncthreads();
    for (int off = 1; off < 256; off <<= 1) {
        int a = 0;
        if (t < 256) { a = sc[t]; if (t >= off) a += sc[t - off]; }
        __syncthreads();
        if (t < 256) sc[t] = a;
        __syncthreads();
    }
    if (t < 256) {
        int ex = sc[t] - h;
        cur[t] = ex;
        int d = (b << D_BITS) + t;
        if (d < N) {
            rowptr[d] = base + ex;
            rend[d]   = base + ex + h;
            dis[d] = (h > 0) ? rsqrtf((float)h) : 0.0f;
        }
    }
    __syncthreads();

    for (int i = t; i < nbk; i += 1024) {
        uint2 pr = pp[i];
        if (pr.x != (unsigned)N) {
            int p = atomicAdd(&cur[pr.y & 255], 1);
            srcs[base + p] = (int)pr.x;
        }
    }
}

// ---- h = bf16(dis * (x @ W)) via MFMA, no LDS -------------------------------
// Block = 4 waves; wave w covers rows mbase+w*32 .. +31, all 128 cols.
__global__ __launch_bounds__(256) void k_gemm(const float* __restrict__ x,
                                              const uint4* __restrict__ Wf,
                                              const float* __restrict__ dis,
                                              unsigned short* __restrict__ h2s,
                                              int N) {
    const int wave = threadIdx.x >> 6;
    const int lane = threadIdx.x & 63;
    const int half = lane >> 5;          // k sub-block 0/1 (8 elems each)
    const int lm   = lane & 31;
    const int mbase = blockIdx.x * 128 + wave * 32;
    const int arow  = min(mbase + lm, N - 1);   // clamp; garbage rows discarded

    const fx4* xr = (const fx4*)(x + (size_t)arow * N_FEAT) + half * 2;

    f32x16 acc0 = {0}, acc1 = {0}, acc2 = {0}, acc3 = {0};

#pragma unroll
    for (int ks = 0; ks < 16; ++ks) {
        fx4 a0 = xr[ks * 4];          // k = ks*16 + half*8 + (0..3)
        fx4 a1 = xr[ks * 4 + 1];      //                  + (4..7)
        union { bf16x8 v; unsigned u[4]; } A;
        A.u[0] = f2bf(a0.x) | (f2bf(a0.y) << 16);
        A.u[1] = f2bf(a0.z) | (f2bf(a0.w) << 16);
        A.u[2] = f2bf(a1.x) | (f2bf(a1.y) << 16);
        A.u[3] = f2bf(a1.z) | (f2bf(a1.w) << 16);
        union { bf16x8 v; uint4 q; } B0, B1, B2, B3;
        B0.q = Wf[(ks * 4 + 0) * 64 + lane];
        B1.q = Wf[(ks * 4 + 1) * 64 + lane];
        B2.q = Wf[(ks * 4 + 2) * 64 + lane];
        B3.q = Wf[(ks * 4 + 3) * 64 + lane];
        acc0 = __builtin_amdgcn_mfma_f32_32x32x16_bf16(A.v, B0.v, acc0, 0, 0, 0);
        acc1 = __builtin_amdgcn_mfma_f32_32x32x16_bf16(A.v, B1.v, acc1, 0, 0, 0);
        acc2 = __builtin_amdgcn_mfma_f32_32x32x16_bf16(A.v, B2.v, acc2, 0, 0, 0);
        acc3 = __builtin_amdgcn_mfma_f32_32x32x16_bf16(A.v, B3.v, acc3, 0, 0, 0);
    }

    // C/D: col = lane&31, row = (r&3) + 8*(r>>2) + 4*(lane>>5)   [m74/m101]
#pragma unroll
    for (int r = 0; r < 16; ++r) {
        int row  = (r & 3) + 8 * (r >> 2) + 4 * half;
        int node = mbase + row;
        if (node < N) {
            float dn = dis[node];
            size_t o = (size_t)node * N_HID + lm;
            h2s[o +  0] = (unsigned short)f2bf(dn * acc0[r]);
            h2s[o + 32] = (unsigned short)f2bf(dn * acc1[r]);
            h2s[o + 64] = (unsigned short)f2bf(dn * acc2[r]);
            h2s[o + 96] = (unsigned short)f2bf(dn * acc3[r]);
        }
    }
}

// ---- aggregation: out[n] = dis[n] * sum(h[srcs]) + bias ---------------------
// One wave per node. 16-edge chunks: one coalesced srcs read, ds_bpermute
// distribution, 4x dwordx4 gathers (each covers 4 edge rows = 1 KB).
// Lane-group j = lane>>4 handles edge 4g+j of the chunk; lane q = lane&15
// holds hidden dims 8q..8q+7. Out-of-segment slots clamp to zero row h2[N].
__global__ __launch_bounds__(256) void k_aggr(const int* __restrict__ rowptr,
                                              const int* __restrict__ rend,
                                              const int* __restrict__ srcs,
                                              const u32x4* __restrict__ h2q,
                                              const float* __restrict__ dis,
                                              const float* __restrict__ bias,
                                              float4* __restrict__ out4, int N) {
    const int n    = blockIdx.x * 4 + (threadIdx.x >> 6);
    const int lane = threadIdx.x & 63;
    if (n >= N) return;
    const int j = lane >> 4;      // edge sub-slot within each gather
    const int q = lane & 15;      // 16B chunk (dims 8q..8q+7) within a row

    int i   = rowptr[n];
    int end = rend[n];
    float dn = dis[n];            // hoisted: overlaps with srcs/gather latency

    float a[8];
#pragma unroll
    for (int k = 0; k < 8; ++k) a[k] = 0.0f;

    for (; i < end; i += 16) {
        // one coalesced 64B read covers 16 src ids (srcs padded allocation)
        int cl = srcs[i + q];
#pragma unroll
        for (int g = 0; g < 4; ++g) {
            int cg  = __shfl(cl, 4 * g + j, 64);   // ds_bpermute
            int idx = i + 4 * g + j;
            cg = (idx < end) ? cg : N;             // dummy zero row for tail
            u32x4 v = h2q[(size_t)cg * 16 + q];    // dwordx4: 4 rows / instr
            a[0] += bf2f(v[0]);  a[1] += bf2f_hi(v[0]);
            a[2] += bf2f(v[1]);  a[3] += bf2f_hi(v[1]);
            a[4] += bf2f(v[2]);  a[5] += bf2f_hi(v[2]);
            a[6] += bf2f(v[3]);  a[7] += bf2f_hi(v[3]);
        }
    }

    // sum the 4 lane-groups (once per node)
#pragma unroll
    for (int k = 0; k < 8; ++k) {
        a[k] += __shfl_xor(a[k], 16, 64);
        a[k] += __shfl_xor(a[k], 32, 64);
    }

    if (lane < 16) {
        const float4* b4 = (const float4*)bias;
        float4 b0 = b4[q * 2], b1 = b4[q * 2 + 1];
        float4 o0, o1;
        o0.x = dn * a[0] + b0.x;  o0.y = dn * a[1] + b0.y;
        o0.z = dn * a[2] + b0.z;  o0.w = dn * a[3] + b0.w;
        o1.x = dn * a[4] + b1.x;  o1.y = dn * a[5] + b1.y;
        o1.z = dn * a[6] + b1.z;  o1.w = dn * a[7] + b1.w;
        out4[(size_t)n * 32 + q * 2]     = o0;
        out4[(size_t)n * 32 + q * 2 + 1] = o1;
    }
}

extern "C" void kernel_launch(void* const* d_in, const int* in_sizes, int n_in,
                              void* d_out, int out_size, void* d_ws, size_t ws_size,
                              hipStream_t stream) {
    const float* x    = (const float*)d_in[0];   // fp32 [N,256]
    const int*   ei   = (const int*)d_in[1];     // int32 [2,E]
    const float* W    = (const float*)d_in[2];   // fp32 [256,128]
    const float* bias = (const float*)d_in[3];   // fp32 [128]

    const int N = in_sizes[0] / N_FEAT;   // 100000
    const int E = in_sizes[1] / 2;        // 1600000
    const int nb = (N + 255) >> D_BITS;   // 391 coarse buckets

    // workspace layout (~57 MB)
    char* ws = (char*)d_ws;
    size_t off = 0;
    int*          gcur   = (int*)(ws + off);   off += 512 * 4;
    int*          cbase  = (int*)(ws + off);   off += 512 * 4;
    int*          rowptr = (int*)(ws + off);   off += (size_t)(N + 4) * 4;
    int*          rend   = (int*)(ws + off);   off += (size_t)(N + 4) * 4;
    float*        dis    = (float*)(ws + off); off += (size_t)N * 4;
    int*          srcs   = (int*)(ws + off);   off += (size_t)nb * CAP * 4 + 64;
    uint4*        Wf     = (uint4*)(ws + off); off += 4096 * 16;   // 64 KB
    uint2*        pairs  = (uint2*)(ws + off); off += (size_t)nb * CAP * 8;
    unsigned int* h2     = (unsigned int*)(ws + off);  // (N+1)*64 dwords

    k_pre<<<17, 256, 0, stream>>>(W, (uint4*)Wf, gcur, h2 + (size_t)N * 64);
    k_part<<<(E + TILE - 1) / TILE, 1024, 0, stream>>>(ei, gcur, pairs, E, nb, N);
    k_scanb<<<1, 256, 0, stream>>>(gcur, cbase, nb);
    k_fine<<<nb, 1024, 0, stream>>>(pairs, gcur, cbase, rowptr, rend, dis,
                                    srcs, N);
    k_gemm<<<(N + 127) / 128, 256, 0, stream>>>(x, Wf, dis,
                                                (unsigned short*)h2, N);
    k_aggr<<<(N + 3) / 4, 256, 0, stream>>>(rowptr, rend, srcs, (const u32x4*)h2,
                                            dis, bias, (float4*)d_out, N);
}